// Round 6
// baseline (5507.568 us; speedup 1.0000x reference)
//
#include <hip/hip_runtime.h>
#include <hip/hip_bf16.h>

using bf16 = __bf16;
typedef __bf16 bf16x8 __attribute__((ext_vector_type(8)));

static constexpr int BATCH = 4;
static constexpr int SEQ   = 2048;
static constexpr int DIN   = 512;
static constexpr int NHEAD = 8;
static constexpr int DMID  = 2048;
static constexpr int MROWS = BATCH * SEQ;   // 8192

// ---------------------------------------------------------------------------
// VALU GEMM:  C[M,N] = act(A[M,K] @ B[K,N]), fp32 accumulate.
// B read in natural [K][N] layout. 64x64 tile, BK=16, 256 threads, 4x4/thread.
// ---------------------------------------------------------------------------
template <typename TA, typename TC, int ACT>
__global__ __launch_bounds__(256) void gemm_valu(const TA* __restrict__ A,
                                                 const float* __restrict__ B,
                                                 TC* __restrict__ C,
                                                 int M, int N, int K)
{
    __shared__ float sAT[16][68];
    __shared__ float sB [16][68];

    const int t  = threadIdx.x;
    const int tx = t & 15;
    const int ty = t >> 4;
    const int m0 = blockIdx.y * 64;
    const int n0 = blockIdx.x * 64;

    float acc[4][4] = {};

    for (int k0 = 0; k0 < K; k0 += 16) {
        for (int i = 0; i < 4; ++i) {
            const int r = (t >> 4) + 16 * i;
            sAT[t & 15][r] = (float)A[(size_t)(m0 + r) * K + k0 + (t & 15)];
        }
        for (int i = 0; i < 4; ++i) {
            const int r = (t >> 6) + 4 * i;
            sB[r][t & 63] = B[(size_t)(k0 + r) * N + n0 + (t & 63)];
        }
        __syncthreads();

        for (int kk = 0; kk < 16; ++kk) {
            const float4 av = *reinterpret_cast<const float4*>(&sAT[kk][ty * 4]);
            const float4 bv = *reinterpret_cast<const float4*>(&sB[kk][tx * 4]);
            const float a[4] = {av.x, av.y, av.z, av.w};
            const float b[4] = {bv.x, bv.y, bv.z, bv.w};
            for (int i = 0; i < 4; ++i)
                for (int j = 0; j < 4; ++j)
                    acc[i][j] += a[i] * b[j];
        }
        __syncthreads();
    }

    for (int i = 0; i < 4; ++i)
        for (int j = 0; j < 4; ++j) {
            float v = acc[i][j];
            if (ACT) v = v > 0.f ? v : 0.f;
            C[(size_t)(m0 + ty * 4 + i) * N + n0 + tx * 4 + j] = (TC)v;
        }
}

// ---------------------------------------------------------------------------
// VALU attention, one wave per (b, h, q-row). Full 2048-score row in registers.
// ---------------------------------------------------------------------------
__global__ __launch_bounds__(256) void attn_valu(const float* __restrict__ Q,
                                                 const float* __restrict__ Km,
                                                 const float* __restrict__ V,
                                                 const float* __restrict__ mask,
                                                 float* __restrict__ O)
{
    __shared__ float wbuf[4][SEQ];

    const int wave = threadIdx.x >> 6;
    const int lane = threadIdx.x & 63;
    const int q    = blockIdx.x * 4 + wave;
    const int h    = blockIdx.y;
    const int b    = blockIdx.z;

    const float* Qr   = Q  + (size_t)(b * SEQ + q) * DIN + h * 64;
    const float* Kh   = Km + (size_t)(b * SEQ) * DIN + h * 64;
    const float* Vh   = V  + (size_t)(b * SEQ) * DIN + h * 64;
    const float* mrow = mask + ((size_t)b * SEQ + q) * SEQ;

    float qreg[64];
    {
        const float4* q4 = reinterpret_cast<const float4*>(Qr);
        for (int d4 = 0; d4 < 16; ++d4) {
            const float4 v = q4[d4];
            qreg[d4 * 4 + 0] = v.x; qreg[d4 * 4 + 1] = v.y;
            qreg[d4 * 4 + 2] = v.z; qreg[d4 * 4 + 3] = v.w;
        }
    }

    float s[32];
    float mx = -3.4e38f;
    for (int i = 0; i < 32; ++i) {
        const int k = i * 64 + lane;
        const float4* K4 = reinterpret_cast<const float4*>(Kh + (size_t)k * DIN);
        float acc = 0.f;
        for (int d4 = 0; d4 < 16; ++d4) {
            const float4 kv = K4[d4];
            acc += qreg[d4 * 4 + 0] * kv.x + qreg[d4 * 4 + 1] * kv.y
                 + qreg[d4 * 4 + 2] * kv.z + qreg[d4 * 4 + 3] * kv.w;
        }
        acc = acc * 0.125f + mrow[k];
        s[i] = acc;
        mx = fmaxf(mx, acc);
    }
    for (int off = 1; off < 64; off <<= 1) mx = fmaxf(mx, __shfl_xor(mx, off));

    float sum = 0.f;
    for (int i = 0; i < 32; ++i) { s[i] = expf(s[i] - mx); sum += s[i]; }
    for (int off = 1; off < 64; off <<= 1) sum += __shfl_xor(sum, off);
    const float inv = 1.f / sum;

    for (int i = 0; i < 32; ++i) wbuf[wave][i * 64 + lane] = s[i] * inv;
    __syncthreads();

    float o = 0.f;
    #pragma unroll 8
    for (int k = 0; k < SEQ; ++k)
        o += wbuf[wave][k] * Vh[(size_t)k * DIN + lane];

    O[(size_t)(b * SEQ + q) * DIN + h * 64 + lane] = o;
}

// ---------------------------------------------------------------------------
// Fused residual add + LayerNorm over D=512. X fp32, Y bf16, out = TO.
// ---------------------------------------------------------------------------
template <typename TO>
__global__ __launch_bounds__(256) void add_ln(const float* __restrict__ X,
                                              const bf16* __restrict__ Y,
                                              TO* __restrict__ Out)
{
    const int row  = blockIdx.x * 4 + (threadIdx.x >> 6);
    const int lane = threadIdx.x & 63;
    const size_t base = (size_t)row * DIN + lane * 8;

    const float4 x0 = *reinterpret_cast<const float4*>(X + base);
    const float4 x1 = *reinterpret_cast<const float4*>(X + base + 4);
    const bf16x8 yv = *reinterpret_cast<const bf16x8*>(Y + base);

    float v[8] = {x0.x, x0.y, x0.z, x0.w, x1.x, x1.y, x1.z, x1.w};
    float s = 0.f;
    for (int i = 0; i < 8; ++i) { v[i] += (float)yv[i]; s += v[i]; }
    for (int off = 1; off < 64; off <<= 1) s += __shfl_xor(s, off);
    const float mu = s * (1.f / DIN);

    float var = 0.f;
    for (int i = 0; i < 8; ++i) { const float d = v[i] - mu; var += d * d; }
    for (int off = 1; off < 64; off <<= 1) var += __shfl_xor(var, off);
    const float rstd = rsqrtf(var * (1.f / DIN) + 1e-5f);

    for (int i = 0; i < 8; ++i)
        Out[base + i] = (TO)((v[i] - mu) * rstd);
}

// ---------------------------------------------------------------------------
// Diagnostic fill (fp32 now).
// ---------------------------------------------------------------------------
__global__ __launch_bounds__(256) void fill_const(float* __restrict__ out,
                                                  float val, int n)
{
    const int i = blockIdx.x * 256 + threadIdx.x;
    if (i < n) out[i] = val;
}

// ---------------------------------------------------------------------------
extern "C" void kernel_launch(void* const* d_in, const int* in_sizes, int n_in,
                              void* d_out, int out_size, void* d_ws, size_t ws_size,
                              hipStream_t stream)
{
    const float* query = (const float*)d_in[0];
    const float* key   = (const float*)d_in[1];
    const float* value = (const float*)d_in[2];
    const float* mask  = (const float*)d_in[3];
    const float* WQ    = (const float*)d_in[4];
    const float* WK    = (const float*)d_in[5];
    const float* WV    = (const float*)d_in[6];
    const float* WO    = (const float*)d_in[7];
    const float* W1    = (const float*)d_in[8];
    const float* W2    = (const float*)d_in[9];

    // Workspace map (16 MiB units):
    //   [ 0,16) Qf -> later Ln1f       [16,32) Kf -> later F2 (bf16, 8 MiB)
    //   [32,64) Vf+Of -> later Mid (bf16, 32 MiB)   [64,72) Twob (bf16)
    char* w = (char*)d_ws;
    const size_t MB16 = (size_t)MROWS * DIN * 4;
    float* Qf   = (float*)(w);
    float* Kf   = (float*)(w + MB16);
    float* Vf   = (float*)(w + 2 * MB16);
    float* Of   = (float*)(w + 3 * MB16);
    bf16*  Twob = (bf16*) (w + 4 * MB16);
    bf16*  Mid  = (bf16*) (w + 2 * MB16);
    bf16*  F2   = (bf16*) (w + MB16);
    float* Ln1f = Qf;

    const dim3 blk(256);

    if (ws_size < 4 * MB16 + ((size_t)MROWS * DIN * 2)) {
        fill_const<<<dim3((out_size + 255) / 256), blk, 0, stream>>>((float*)d_out, 7000.f, out_size);
        return;
    }

    // projections (B in natural [K][N] layout)
    gemm_valu<float, float, 0><<<dim3(DIN / 64, MROWS / 64), blk, 0, stream>>>(query, WQ, Qf, MROWS, DIN, DIN);
    gemm_valu<float, float, 0><<<dim3(DIN / 64, MROWS / 64), blk, 0, stream>>>(key,   WK, Kf, MROWS, DIN, DIN);
    gemm_valu<float, float, 0><<<dim3(DIN / 64, MROWS / 64), blk, 0, stream>>>(value, WV, Vf, MROWS, DIN, DIN);

    // attention
    attn_valu<<<dim3(SEQ / 4, NHEAD, BATCH), blk, 0, stream>>>(Qf, Kf, Vf, mask, Of);

    // output projection + residual + LN
    gemm_valu<float, bf16, 0><<<dim3(DIN / 64, MROWS / 64), blk, 0, stream>>>(Of, WO, Twob, MROWS, DIN, DIN);
    add_ln<float><<<dim3(MROWS / 4), blk, 0, stream>>>(query, Twob, Ln1f);

    // FFN
    gemm_valu<float, bf16, 1><<<dim3(DMID / 64, MROWS / 64), blk, 0, stream>>>(Ln1f, W1, Mid, MROWS, DMID, DIN);
    gemm_valu<bf16, bf16, 0><<<dim3(DIN / 64, MROWS / 64), blk, 0, stream>>>(Mid, W2, F2, MROWS, DIN, DMID);

    // final residual + LN -> fp32 output (reference returns float32!)
    add_ln<float><<<dim3(MROWS / 4), blk, 0, stream>>>(Ln1f, F2, (float*)d_out);
}

// Round 7
// 489.304 us; speedup vs baseline: 11.2559x; 11.2559x over previous
//
#include <hip/hip_runtime.h>
#include <hip/hip_bf16.h>

using bf16 = __bf16;
typedef __bf16 bf16x4 __attribute__((ext_vector_type(4)));
typedef __bf16 bf16x8 __attribute__((ext_vector_type(8)));
typedef float f32x4 __attribute__((ext_vector_type(4)));

static constexpr int BATCH = 4;
static constexpr int SEQ   = 2048;
static constexpr int DIN   = 512;
static constexpr int NHEAD = 8;
static constexpr int DMID  = 2048;
static constexpr int MROWS = BATCH * SEQ;   // 8192

// ---------------------------------------------------------------------------
// fp32 -> bf16 elementwise cast (4 elems/thread)
// ---------------------------------------------------------------------------
__global__ __launch_bounds__(256) void cast_f2b(const float* __restrict__ in,
                                                bf16* __restrict__ out, int n)
{
    const int i = (blockIdx.x * 256 + threadIdx.x) * 4;
    if (i >= n) return;
    const float4 v = *reinterpret_cast<const float4*>(in + i);
    bf16x4 o;
    o[0] = (bf16)v.x; o[1] = (bf16)v.y; o[2] = (bf16)v.z; o[3] = (bf16)v.w;
    *reinterpret_cast<bf16x4*>(out + i) = o;
}

// ---------------------------------------------------------------------------
// fp32 [R][C] -> bf16 transposed [C][R].  Grid (C/32, R/32).
// ---------------------------------------------------------------------------
__global__ __launch_bounds__(256) void transpose_f2b(const float* __restrict__ in,
                                                     bf16* __restrict__ out,
                                                     int ip, int op)
{
    __shared__ float tile[32][33];
    const int c0 = blockIdx.x * 32;
    const int r0 = blockIdx.y * 32;
    const int tx = threadIdx.x & 31;
    const int ty = threadIdx.x >> 5;
    for (int i = 0; i < 32; i += 8)
        tile[ty + i][tx] = in[(size_t)(r0 + ty + i) * ip + c0 + tx];
    __syncthreads();
    for (int i = 0; i < 32; i += 8)
        out[(size_t)(c0 + ty + i) * op + r0 + tx] = (bf16)tile[tx][ty + i];
}

// ---------------------------------------------------------------------------
// bf16 [R][C] -> bf16 transposed [C][R].  Grid (C/32, R/32).
// ---------------------------------------------------------------------------
__global__ __launch_bounds__(256) void transpose_b2b(const bf16* __restrict__ in,
                                                     bf16* __restrict__ out,
                                                     int ip, int op)
{
    __shared__ bf16 tile[32][33];
    const int c0 = blockIdx.x * 32;
    const int r0 = blockIdx.y * 32;
    const int tx = threadIdx.x & 31;
    const int ty = threadIdx.x >> 5;
    for (int i = 0; i < 32; i += 8)
        tile[ty + i][tx] = in[(size_t)(r0 + ty + i) * ip + c0 + tx];
    __syncthreads();
    for (int i = 0; i < 32; i += 8)
        out[(size_t)(c0 + ty + i) * op + r0 + tx] = tile[tx][ty + i];
}

// ---------------------------------------------------------------------------
// Tiled bf16 MFMA GEMM:  C[M,N] = act(A[M,K] @ Bt[N,K]^T), fp32 accumulate.
// 128x128 tile, BK=32, 4 waves (2x2), each wave 64x64 via 4x4 of 16x16x32.
// A/B frag: (lane&15, (lane>>4)*8+j); C/D: col=lane&15, row=(lane>>4)*4+j.
// Validated: R2 (this kernel) == R4 (VALU reference) bit-identical.
// ---------------------------------------------------------------------------
template <int ACT>
__global__ __launch_bounds__(256) void gemm_bt(const bf16* __restrict__ A,
                                               const bf16* __restrict__ Bt,
                                               bf16* __restrict__ C,
                                               int M, int N, int K)
{
    __shared__ bf16 sA[128 * 32];
    __shared__ bf16 sB[128 * 32];

    const int t    = threadIdx.x;
    const int lane = t & 63;
    const int wave = t >> 6;
    const int wm   = wave >> 1;
    const int wn   = wave & 1;
    const int lr   = lane & 15;
    const int lq   = lane >> 4;

    const int m0 = blockIdx.y * 128;
    const int n0 = blockIdx.x * 128;

    const int srow = t >> 2;
    const int scol = (t & 3) << 3;

    f32x4 acc[4][4] = {};

    for (int k0 = 0; k0 < K; k0 += 32) {
        int4 a0 = *reinterpret_cast<const int4*>(A  + (size_t)(m0 + srow)      * K + k0 + scol);
        int4 a1 = *reinterpret_cast<const int4*>(A  + (size_t)(m0 + srow + 64) * K + k0 + scol);
        int4 b0 = *reinterpret_cast<const int4*>(Bt + (size_t)(n0 + srow)      * K + k0 + scol);
        int4 b1 = *reinterpret_cast<const int4*>(Bt + (size_t)(n0 + srow + 64) * K + k0 + scol);
        *reinterpret_cast<int4*>(&sA[srow * 32 + scol])        = a0;
        *reinterpret_cast<int4*>(&sA[(srow + 64) * 32 + scol]) = a1;
        *reinterpret_cast<int4*>(&sB[srow * 32 + scol])        = b0;
        *reinterpret_cast<int4*>(&sB[(srow + 64) * 32 + scol]) = b1;
        __syncthreads();

        bf16x8 af[4], bfr[4];
        for (int i = 0; i < 4; ++i)
            af[i]  = *reinterpret_cast<const bf16x8*>(&sA[(wm * 64 + i * 16 + lr) * 32 + lq * 8]);
        for (int i = 0; i < 4; ++i)
            bfr[i] = *reinterpret_cast<const bf16x8*>(&sB[(wn * 64 + i * 16 + lr) * 32 + lq * 8]);
        for (int mi = 0; mi < 4; ++mi)
            for (int ni = 0; ni < 4; ++ni)
                acc[mi][ni] = __builtin_amdgcn_mfma_f32_16x16x32_bf16(af[mi], bfr[ni], acc[mi][ni], 0, 0, 0);
        __syncthreads();
    }

    for (int mi = 0; mi < 4; ++mi)
        for (int ni = 0; ni < 4; ++ni) {
            const int col = n0 + wn * 64 + ni * 16 + lr;
            for (int j = 0; j < 4; ++j) {
                const int row = m0 + wm * 64 + mi * 16 + lq * 4 + j;
                float v = acc[mi][ni][j];
                if (ACT == 1) v = v > 0.f ? v : 0.f;
                C[(size_t)row * N + col] = (bf16)v;
            }
        }
}

// ---------------------------------------------------------------------------
// Flash attention (MFMA). Block = (q-tile 64, head, batch), 4 waves x 16 rows.
// Qb/Kb: [B*L, 512] (cols h*64+d). Vt: [512, B*L] (rows h*64+d). mask fp32.
// Validated vs VALU reference (bit-identity R2==R4).
// ---------------------------------------------------------------------------
__global__ __launch_bounds__(256) void attn_kernel(const bf16* __restrict__ Qb,
                                                   const bf16* __restrict__ Kb,
                                                   const bf16* __restrict__ Vt,
                                                   const float* __restrict__ mask,
                                                   bf16* __restrict__ O)
{
    const int qt = blockIdx.x;
    const int h  = blockIdx.y;
    const int b  = blockIdx.z;

    const int t    = threadIdx.x;
    const int lane = t & 63;
    const int wave = t >> 6;
    const int lr   = lane & 15;
    const int lq   = lane >> 4;
    const int q0   = qt * 64;

    __shared__ bf16 sK[64 * 64];
    __shared__ bf16 sV[64 * 64];
    __shared__ bf16 sP[4][16 * 64];

    const int  qrow = q0 + wave * 16 + lr;
    const bf16* qp  = Qb + (size_t)(b * SEQ + qrow) * DIN + h * 64 + lq * 8;
    const bf16x8 qf0 = *reinterpret_cast<const bf16x8*>(qp);
    const bf16x8 qf1 = *reinterpret_cast<const bf16x8*>(qp + 32);

    f32x4 o[4] = {};
    float mrow[4] = {-__builtin_inff(), -__builtin_inff(), -__builtin_inff(), -__builtin_inff()};
    float lrow[4] = {0.f, 0.f, 0.f, 0.f};

    const int sr = t >> 2;
    const int sc = (t & 3) << 3;

    constexpr float LOG2E = 1.4426950408889634f;

    for (int k0 = 0; k0 < SEQ; k0 += 64) {
        for (int r = 0; r < 2; ++r) {
            const int c = sc + r * 32;
            *reinterpret_cast<int4*>(&sK[sr * 64 + c]) =
                *reinterpret_cast<const int4*>(Kb + (size_t)(b * SEQ + k0 + sr) * DIN + h * 64 + c);
            *reinterpret_cast<int4*>(&sV[sr * 64 + c]) =
                *reinterpret_cast<const int4*>(Vt + (size_t)(h * 64 + sr) * MROWS + b * SEQ + k0 + c);
        }
        __syncthreads();

        f32x4 sf[4] = {};
        for (int s = 0; s < 2; ++s) {
            const bf16x8 qf = s ? qf1 : qf0;
            for (int ni = 0; ni < 4; ++ni) {
                bf16x8 kf = *reinterpret_cast<const bf16x8*>(&sK[(ni * 16 + lr) * 64 + s * 32 + lq * 8]);
                sf[ni] = __builtin_amdgcn_mfma_f32_16x16x32_bf16(qf, kf, sf[ni], 0, 0, 0);
            }
        }

        float sv[4][4];
        float rmax[4];
        for (int j = 0; j < 4; ++j) {
            const float* mp = mask + ((size_t)b * SEQ + (q0 + wave * 16 + lq * 4 + j)) * SEQ + k0;
            float mx = -__builtin_inff();
            for (int ni = 0; ni < 4; ++ni) {
                float v = sf[ni][j] * 0.125f + mp[ni * 16 + lr];
                sv[ni][j] = v;
                mx = fmaxf(mx, v);
            }
            rmax[j] = mx;
        }
        for (int off = 1; off < 16; off <<= 1)
            for (int j = 0; j < 4; ++j)
                rmax[j] = fmaxf(rmax[j], __shfl_xor(rmax[j], off));

        float alpha[4], rsum[4];
        for (int j = 0; j < 4; ++j) {
            const float mnew = fmaxf(mrow[j], rmax[j]);
            alpha[j] = exp2f((mrow[j] - mnew) * LOG2E);
            mrow[j]  = mnew;
            float ssum = 0.f;
            for (int ni = 0; ni < 4; ++ni) {
                float p = exp2f((sv[ni][j] - mnew) * LOG2E);
                sv[ni][j] = p;
                ssum += p;
            }
            rsum[j] = ssum;
        }
        for (int off = 1; off < 16; off <<= 1)
            for (int j = 0; j < 4; ++j)
                rsum[j] += __shfl_xor(rsum[j], off);

        for (int j = 0; j < 4; ++j)
            lrow[j] = lrow[j] * alpha[j] + rsum[j];
        for (int ni = 0; ni < 4; ++ni)
            for (int j = 0; j < 4; ++j)
                o[ni][j] *= alpha[j];

        for (int ni = 0; ni < 4; ++ni)
            for (int j = 0; j < 4; ++j)
                sP[wave][(lq * 4 + j) * 64 + ni * 16 + lr] = (bf16)sv[ni][j];

        for (int s = 0; s < 2; ++s) {
            bf16x8 pf = *reinterpret_cast<const bf16x8*>(&sP[wave][lr * 64 + s * 32 + lq * 8]);
            for (int ni = 0; ni < 4; ++ni) {
                bf16x8 vf = *reinterpret_cast<const bf16x8*>(&sV[(ni * 16 + lr) * 64 + s * 32 + lq * 8]);
                o[ni] = __builtin_amdgcn_mfma_f32_16x16x32_bf16(pf, vf, o[ni], 0, 0, 0);
            }
        }
        __syncthreads();
    }

    for (int ni = 0; ni < 4; ++ni)
        for (int j = 0; j < 4; ++j) {
            const int row = q0 + wave * 16 + lq * 4 + j;
            const int col = h * 64 + ni * 16 + lr;
            O[(size_t)(b * SEQ + row) * DIN + col] = (bf16)(o[ni][j] / lrow[j]);
        }
}

// ---------------------------------------------------------------------------
// Fused residual add + LayerNorm over D=512. X fp32, Y bf16.
// Writes bf16 (if Ob) and fp32 (if Of). One wave per row.
// ---------------------------------------------------------------------------
__global__ __launch_bounds__(256) void add_ln(const float* __restrict__ X,
                                              const bf16* __restrict__ Y,
                                              bf16* __restrict__ Ob,
                                              float* __restrict__ Of)
{
    const int row  = blockIdx.x * 4 + (threadIdx.x >> 6);
    const int lane = threadIdx.x & 63;
    const size_t base = (size_t)row * DIN + lane * 8;
    const float4 x0 = *reinterpret_cast<const float4*>(X + base);
    const float4 x1 = *reinterpret_cast<const float4*>(X + base + 4);
    const bf16x8 yv = *reinterpret_cast<const bf16x8*>(Y + base);
    float v[8] = {x0.x, x0.y, x0.z, x0.w, x1.x, x1.y, x1.z, x1.w};
    float s = 0.f;
    for (int i = 0; i < 8; ++i) { v[i] += (float)yv[i]; s += v[i]; }
    for (int off = 1; off < 64; off <<= 1) s += __shfl_xor(s, off);
    const float mu = s * (1.f / DIN);
    float var = 0.f;
    for (int i = 0; i < 8; ++i) { const float d = v[i] - mu; var += d * d; }
    for (int off = 1; off < 64; off <<= 1) var += __shfl_xor(var, off);
    const float rstd = rsqrtf(var * (1.f / DIN) + 1e-5f);
    float r[8];
    for (int i = 0; i < 8; ++i) r[i] = (v[i] - mu) * rstd;
    if (Ob) {
        bf16x8 ov;
        for (int i = 0; i < 8; ++i) ov[i] = (bf16)r[i];
        *reinterpret_cast<bf16x8*>(Ob + base) = ov;
    }
    if (Of) {
        *reinterpret_cast<float4*>(Of + base)     = make_float4(r[0], r[1], r[2], r[3]);
        *reinterpret_cast<float4*>(Of + base + 4) = make_float4(r[4], r[5], r[6], r[7]);
    }
}

// ---------------------------------------------------------------------------
extern "C" void kernel_launch(void* const* d_in, const int* in_sizes, int n_in,
                              void* d_out, int out_size, void* d_ws, size_t ws_size,
                              hipStream_t stream)
{
    const float* query = (const float*)d_in[0];
    const float* key   = (const float*)d_in[1];
    const float* value = (const float*)d_in[2];
    const float* mask  = (const float*)d_in[3];
    const float* WQ    = (const float*)d_in[4];
    const float* WK    = (const float*)d_in[5];
    const float* WV    = (const float*)d_in[6];
    const float* WO    = (const float*)d_in[7];
    const float* W1    = (const float*)d_in[8];
    const float* W2    = (const float*)d_in[9];

    char* w = (char*)d_ws;
    size_t off = 0;
    auto carve2 = [&](size_t elems) { bf16* p = (bf16*)(w + off); off += elems * 2; return p; };
    auto carve4 = [&](size_t elems) { float* p = (float*)(w + off); off += elems * 4; return p; };

    bf16* qc    = carve2((size_t)MROWS * DIN);
    bf16* kc    = carve2((size_t)MROWS * DIN);
    bf16* vc    = carve2((size_t)MROWS * DIN);
    bf16* Qb    = carve2((size_t)MROWS * DIN);
    bf16* Kb    = carve2((size_t)MROWS * DIN);
    bf16* Vb    = carve2((size_t)MROWS * DIN);
    bf16* Vt    = carve2((size_t)MROWS * DIN);
    bf16* Mid   = carve2((size_t)MROWS * DMID);
    float* Ln1f = carve4((size_t)MROWS * DIN);
    bf16* WQt   = carve2((size_t)DIN * DIN);
    bf16* WKt   = carve2((size_t)DIN * DIN);
    bf16* WVt   = carve2((size_t)DIN * DIN);
    bf16* WOt   = carve2((size_t)DIN * DIN);
    bf16* W1t   = carve2((size_t)DIN * DMID);
    bf16* W2t   = carve2((size_t)DMID * DIN);
    if (off > ws_size) return;

    // aliases of dead buffers
    bf16* Ob   = qc;   // attention output (qc dead after Q projection)
    bf16* Two  = kc;   // WO-proj output  (kc dead after K projection)
    bf16* Ln1b = vc;   // LN1 bf16        (vc dead after V projection)
    bf16* F2   = Vb;   // FFN output      (Vb dead after V transpose)

    const dim3 blk(256);
    const int nqkv = MROWS * DIN;

    // input casts -> bf16
    cast_f2b<<<dim3(nqkv / 1024), blk, 0, stream>>>(query, qc, nqkv);
    cast_f2b<<<dim3(nqkv / 1024), blk, 0, stream>>>(key,   kc, nqkv);
    cast_f2b<<<dim3(nqkv / 1024), blk, 0, stream>>>(value, vc, nqkv);

    // weight cast+transpose to [n][k]
    transpose_f2b<<<dim3(DIN / 32, DIN / 32), blk, 0, stream>>>(WQ, WQt, DIN, DIN);
    transpose_f2b<<<dim3(DIN / 32, DIN / 32), blk, 0, stream>>>(WK, WKt, DIN, DIN);
    transpose_f2b<<<dim3(DIN / 32, DIN / 32), blk, 0, stream>>>(WV, WVt, DIN, DIN);
    transpose_f2b<<<dim3(DIN / 32, DIN / 32), blk, 0, stream>>>(WO, WOt, DIN, DIN);
    transpose_f2b<<<dim3(DMID / 32, DIN / 32), blk, 0, stream>>>(W1, W1t, DMID, DIN);
    transpose_f2b<<<dim3(DIN / 32, DMID / 32), blk, 0, stream>>>(W2, W2t, DIN, DMID);

    // projections
    gemm_bt<0><<<dim3(DIN / 128, MROWS / 128), blk, 0, stream>>>(qc, WQt, Qb, MROWS, DIN, DIN);
    gemm_bt<0><<<dim3(DIN / 128, MROWS / 128), blk, 0, stream>>>(kc, WKt, Kb, MROWS, DIN, DIN);
    gemm_bt<0><<<dim3(DIN / 128, MROWS / 128), blk, 0, stream>>>(vc, WVt, Vb, MROWS, DIN, DIN);

    // V -> Vt[h*64+d][b*L+l]
    transpose_b2b<<<dim3(DIN / 32, MROWS / 32), blk, 0, stream>>>(Vb, Vt, DIN, MROWS);

    // attention
    attn_kernel<<<dim3(SEQ / 64, NHEAD, BATCH), blk, 0, stream>>>(Qb, Kb, Vt, mask, Ob);

    // output projection + residual + LN (keep fp32 copy for residual 2)
    gemm_bt<0><<<dim3(DIN / 128, MROWS / 128), blk, 0, stream>>>(Ob, WOt, Two, MROWS, DIN, DIN);
    add_ln<<<dim3(MROWS / 4), blk, 0, stream>>>(query, Two, Ln1b, Ln1f);

    // FFN
    gemm_bt<1><<<dim3(DMID / 128, MROWS / 128), blk, 0, stream>>>(Ln1b, W1t, Mid, MROWS, DMID, DIN);
    gemm_bt<0><<<dim3(DIN / 128, MROWS / 128), blk, 0, stream>>>(Mid, W2t, F2, MROWS, DIN, DMID);

    // final residual + LN -> fp32 output
    add_ln<<<dim3(MROWS / 4), blk, 0, stream>>>(Ln1f, F2, (bf16*)nullptr, (float*)d_out);
}

// Round 8
// 440.171 us; speedup vs baseline: 12.5123x; 1.1116x over previous
//
#include <hip/hip_runtime.h>
#include <hip/hip_bf16.h>

using bf16 = __bf16;
typedef __bf16 bf16x4 __attribute__((ext_vector_type(4)));
typedef __bf16 bf16x8 __attribute__((ext_vector_type(8)));
typedef float f32x4 __attribute__((ext_vector_type(4)));

static constexpr int BATCH = 4;
static constexpr int SEQ   = 2048;
static constexpr int DIN   = 512;
static constexpr int NHEAD = 8;
static constexpr int DMID  = 2048;
static constexpr int MROWS = BATCH * SEQ;   // 8192

// ---------------------------------------------------------------------------
// fp32 -> bf16 elementwise cast (4 elems/thread)
// ---------------------------------------------------------------------------
__global__ __launch_bounds__(256) void cast_f2b(const float* __restrict__ in,
                                                bf16* __restrict__ out, int n)
{
    const int i = (blockIdx.x * 256 + threadIdx.x) * 4;
    if (i >= n) return;
    const float4 v = *reinterpret_cast<const float4*>(in + i);
    bf16x4 o;
    o[0] = (bf16)v.x; o[1] = (bf16)v.y; o[2] = (bf16)v.z; o[3] = (bf16)v.w;
    *reinterpret_cast<bf16x4*>(out + i) = o;
}

// ---------------------------------------------------------------------------
// fp32 [R][C] -> bf16 transposed [C][R].  Grid (C/32, R/32).
// ---------------------------------------------------------------------------
__global__ __launch_bounds__(256) void transpose_f2b(const float* __restrict__ in,
                                                     bf16* __restrict__ out,
                                                     int ip, int op)
{
    __shared__ float tile[32][33];
    const int c0 = blockIdx.x * 32;
    const int r0 = blockIdx.y * 32;
    const int tx = threadIdx.x & 31;
    const int ty = threadIdx.x >> 5;
    for (int i = 0; i < 32; i += 8)
        tile[ty + i][tx] = in[(size_t)(r0 + ty + i) * ip + c0 + tx];
    __syncthreads();
    for (int i = 0; i < 32; i += 8)
        out[(size_t)(c0 + ty + i) * op + r0 + tx] = (bf16)tile[tx][ty + i];
}

// ---------------------------------------------------------------------------
// bf16 [R][C] -> bf16 transposed [C][R].  Grid (C/32, R/32).
// ---------------------------------------------------------------------------
__global__ __launch_bounds__(256) void transpose_b2b(const bf16* __restrict__ in,
                                                     bf16* __restrict__ out,
                                                     int ip, int op)
{
    __shared__ bf16 tile[32][33];
    const int c0 = blockIdx.x * 32;
    const int r0 = blockIdx.y * 32;
    const int tx = threadIdx.x & 31;
    const int ty = threadIdx.x >> 5;
    for (int i = 0; i < 32; i += 8)
        tile[ty + i][tx] = in[(size_t)(r0 + ty + i) * ip + c0 + tx];
    __syncthreads();
    for (int i = 0; i < 32; i += 8)
        out[(size_t)(c0 + ty + i) * op + r0 + tx] = tile[tx][ty + i];
}

// ---------------------------------------------------------------------------
// 128x128 MFMA GEMM (for N>=1024 shapes). BK=32, LDS stride padded 32->40
// (banks 4*(5*lr+lq) mod 32, gcd(5,8)=1 -> balanced).
// ---------------------------------------------------------------------------
template <int ACT>
__global__ __launch_bounds__(256) void gemm_bt(const bf16* __restrict__ A,
                                               const bf16* __restrict__ Bt,
                                               bf16* __restrict__ C,
                                               int M, int N, int K)
{
    __shared__ bf16 sA[128 * 40];
    __shared__ bf16 sB[128 * 40];

    const int t    = threadIdx.x;
    const int lane = t & 63;
    const int wave = t >> 6;
    const int wm   = wave >> 1;
    const int wn   = wave & 1;
    const int lr   = lane & 15;
    const int lq   = lane >> 4;

    const int m0 = blockIdx.y * 128;
    const int n0 = blockIdx.x * 128;

    const int srow = t >> 2;
    const int scol = (t & 3) << 3;

    f32x4 acc[4][4] = {};

    for (int k0 = 0; k0 < K; k0 += 32) {
        int4 a0 = *reinterpret_cast<const int4*>(A  + (size_t)(m0 + srow)      * K + k0 + scol);
        int4 a1 = *reinterpret_cast<const int4*>(A  + (size_t)(m0 + srow + 64) * K + k0 + scol);
        int4 b0 = *reinterpret_cast<const int4*>(Bt + (size_t)(n0 + srow)      * K + k0 + scol);
        int4 b1 = *reinterpret_cast<const int4*>(Bt + (size_t)(n0 + srow + 64) * K + k0 + scol);
        *reinterpret_cast<int4*>(&sA[srow * 40 + scol])        = a0;
        *reinterpret_cast<int4*>(&sA[(srow + 64) * 40 + scol]) = a1;
        *reinterpret_cast<int4*>(&sB[srow * 40 + scol])        = b0;
        *reinterpret_cast<int4*>(&sB[(srow + 64) * 40 + scol]) = b1;
        __syncthreads();

        bf16x8 af[4], bfr[4];
        for (int i = 0; i < 4; ++i)
            af[i]  = *reinterpret_cast<const bf16x8*>(&sA[(wm * 64 + i * 16 + lr) * 40 + lq * 8]);
        for (int i = 0; i < 4; ++i)
            bfr[i] = *reinterpret_cast<const bf16x8*>(&sB[(wn * 64 + i * 16 + lr) * 40 + lq * 8]);
        for (int mi = 0; mi < 4; ++mi)
            for (int ni = 0; ni < 4; ++ni)
                acc[mi][ni] = __builtin_amdgcn_mfma_f32_16x16x32_bf16(af[mi], bfr[ni], acc[mi][ni], 0, 0, 0);
        __syncthreads();
    }

    for (int mi = 0; mi < 4; ++mi)
        for (int ni = 0; ni < 4; ++ni) {
            const int col = n0 + wn * 64 + ni * 16 + lr;
            for (int j = 0; j < 4; ++j) {
                const int row = m0 + wm * 64 + mi * 16 + lq * 4 + j;
                float v = acc[mi][ni][j];
                if (ACT == 1) v = v > 0.f ? v : 0.f;
                C[(size_t)row * N + col] = (bf16)v;
            }
        }
}

// ---------------------------------------------------------------------------
// 64x64 MFMA GEMM for skinny-N shapes (N=512): grid M/64 x N/64 = 1024 blocks
// -> 4 blocks/CU (50% occupancy). BK=64, LDS stride 72 (conflict-balanced).
// 4 waves (2x2), each wave 32x32 via 2x2 MFMA, 8 MFMA per k-stage.
// ---------------------------------------------------------------------------
template <int ACT>
__global__ __launch_bounds__(256) void gemm64(const bf16* __restrict__ A,
                                              const bf16* __restrict__ Bt,
                                              bf16* __restrict__ C,
                                              int M, int N, int K)
{
    __shared__ bf16 sA[64 * 72];
    __shared__ bf16 sB[64 * 72];

    const int t    = threadIdx.x;
    const int lane = t & 63;
    const int wave = t >> 6;
    const int wm   = wave >> 1;
    const int wn   = wave & 1;
    const int lr   = lane & 15;
    const int lq   = lane >> 4;

    const int m0 = blockIdx.y * 64;
    const int n0 = blockIdx.x * 64;

    const int srow = t >> 2;          // 0..63
    const int scol = (t & 3) << 4;    // 0,16,32,48

    f32x4 acc[2][2] = {};

    for (int k0 = 0; k0 < K; k0 += 64) {
        int4 a0 = *reinterpret_cast<const int4*>(A  + (size_t)(m0 + srow) * K + k0 + scol);
        int4 a1 = *reinterpret_cast<const int4*>(A  + (size_t)(m0 + srow) * K + k0 + scol + 8);
        int4 b0 = *reinterpret_cast<const int4*>(Bt + (size_t)(n0 + srow) * K + k0 + scol);
        int4 b1 = *reinterpret_cast<const int4*>(Bt + (size_t)(n0 + srow) * K + k0 + scol + 8);
        *reinterpret_cast<int4*>(&sA[srow * 72 + scol])     = a0;
        *reinterpret_cast<int4*>(&sA[srow * 72 + scol + 8]) = a1;
        *reinterpret_cast<int4*>(&sB[srow * 72 + scol])     = b0;
        *reinterpret_cast<int4*>(&sB[srow * 72 + scol + 8]) = b1;
        __syncthreads();

        for (int kk = 0; kk < 2; ++kk) {
            bf16x8 af[2], bfr[2];
            for (int i = 0; i < 2; ++i)
                af[i]  = *reinterpret_cast<const bf16x8*>(&sA[(wm * 32 + i * 16 + lr) * 72 + kk * 32 + lq * 8]);
            for (int i = 0; i < 2; ++i)
                bfr[i] = *reinterpret_cast<const bf16x8*>(&sB[(wn * 32 + i * 16 + lr) * 72 + kk * 32 + lq * 8]);
            for (int mi = 0; mi < 2; ++mi)
                for (int ni = 0; ni < 2; ++ni)
                    acc[mi][ni] = __builtin_amdgcn_mfma_f32_16x16x32_bf16(af[mi], bfr[ni], acc[mi][ni], 0, 0, 0);
        }
        __syncthreads();
    }

    for (int mi = 0; mi < 2; ++mi)
        for (int ni = 0; ni < 2; ++ni) {
            const int col = n0 + wn * 32 + ni * 16 + lr;
            for (int j = 0; j < 4; ++j) {
                const int row = m0 + wm * 32 + mi * 16 + lq * 4 + j;
                float v = acc[mi][ni][j];
                if (ACT == 1) v = v > 0.f ? v : 0.f;
                C[(size_t)row * N + col] = (bf16)v;
            }
        }
}

// ---------------------------------------------------------------------------
// Flash attention (MFMA), LDS rows padded 64->72 (bank-balanced ds_read_b128).
// Block = (q-tile 64, head, batch), 4 waves x 16 rows. Math identical to the
// R2/R7 kernel (validated bit-identical vs VALU reference).
// ---------------------------------------------------------------------------
__global__ __launch_bounds__(256) void attn_kernel(const bf16* __restrict__ Qb,
                                                   const bf16* __restrict__ Kb,
                                                   const bf16* __restrict__ Vt,
                                                   const float* __restrict__ mask,
                                                   bf16* __restrict__ O)
{
    const int qt = blockIdx.x;
    const int h  = blockIdx.y;
    const int b  = blockIdx.z;

    const int t    = threadIdx.x;
    const int lane = t & 63;
    const int wave = t >> 6;
    const int lr   = lane & 15;
    const int lq   = lane >> 4;
    const int q0   = qt * 64;

    __shared__ bf16 sK[64 * 72];
    __shared__ bf16 sV[64 * 72];
    __shared__ bf16 sP[4][16 * 72];

    const int  qrow = q0 + wave * 16 + lr;
    const bf16* qp  = Qb + (size_t)(b * SEQ + qrow) * DIN + h * 64 + lq * 8;
    const bf16x8 qf0 = *reinterpret_cast<const bf16x8*>(qp);
    const bf16x8 qf1 = *reinterpret_cast<const bf16x8*>(qp + 32);

    f32x4 o[4] = {};
    float mrow[4] = {-__builtin_inff(), -__builtin_inff(), -__builtin_inff(), -__builtin_inff()};
    float lrow[4] = {0.f, 0.f, 0.f, 0.f};

    const int sr = t >> 2;
    const int sc = (t & 3) << 3;

    constexpr float LOG2E = 1.4426950408889634f;

    for (int k0 = 0; k0 < SEQ; k0 += 64) {
        for (int r = 0; r < 2; ++r) {
            const int c = sc + r * 32;
            *reinterpret_cast<int4*>(&sK[sr * 72 + c]) =
                *reinterpret_cast<const int4*>(Kb + (size_t)(b * SEQ + k0 + sr) * DIN + h * 64 + c);
            *reinterpret_cast<int4*>(&sV[sr * 72 + c]) =
                *reinterpret_cast<const int4*>(Vt + (size_t)(h * 64 + sr) * MROWS + b * SEQ + k0 + c);
        }
        __syncthreads();

        f32x4 sf[4] = {};
        for (int s = 0; s < 2; ++s) {
            const bf16x8 qf = s ? qf1 : qf0;
            for (int ni = 0; ni < 4; ++ni) {
                bf16x8 kf = *reinterpret_cast<const bf16x8*>(&sK[(ni * 16 + lr) * 72 + s * 32 + lq * 8]);
                sf[ni] = __builtin_amdgcn_mfma_f32_16x16x32_bf16(qf, kf, sf[ni], 0, 0, 0);
            }
        }

        float sv[4][4];
        float rmax[4];
        for (int j = 0; j < 4; ++j) {
            const float* mp = mask + ((size_t)b * SEQ + (q0 + wave * 16 + lq * 4 + j)) * SEQ + k0;
            float mx = -__builtin_inff();
            for (int ni = 0; ni < 4; ++ni) {
                float v = sf[ni][j] * 0.125f + mp[ni * 16 + lr];
                sv[ni][j] = v;
                mx = fmaxf(mx, v);
            }
            rmax[j] = mx;
        }
        for (int off = 1; off < 16; off <<= 1)
            for (int j = 0; j < 4; ++j)
                rmax[j] = fmaxf(rmax[j], __shfl_xor(rmax[j], off));

        float alpha[4], rsum[4];
        for (int j = 0; j < 4; ++j) {
            const float mnew = fmaxf(mrow[j], rmax[j]);
            alpha[j] = exp2f((mrow[j] - mnew) * LOG2E);
            mrow[j]  = mnew;
            float ssum = 0.f;
            for (int ni = 0; ni < 4; ++ni) {
                float p = exp2f((sv[ni][j] - mnew) * LOG2E);
                sv[ni][j] = p;
                ssum += p;
            }
            rsum[j] = ssum;
        }
        for (int off = 1; off < 16; off <<= 1)
            for (int j = 0; j < 4; ++j)
                rsum[j] += __shfl_xor(rsum[j], off);

        for (int j = 0; j < 4; ++j)
            lrow[j] = lrow[j] * alpha[j] + rsum[j];
        for (int ni = 0; ni < 4; ++ni)
            for (int j = 0; j < 4; ++j)
                o[ni][j] *= alpha[j];

        for (int ni = 0; ni < 4; ++ni)
            for (int j = 0; j < 4; ++j)
                sP[wave][(lq * 4 + j) * 72 + ni * 16 + lr] = (bf16)sv[ni][j];

        for (int s = 0; s < 2; ++s) {
            bf16x8 pf = *reinterpret_cast<const bf16x8*>(&sP[wave][lr * 72 + s * 32 + lq * 8]);
            for (int ni = 0; ni < 4; ++ni) {
                bf16x8 vf = *reinterpret_cast<const bf16x8*>(&sV[(ni * 16 + lr) * 72 + s * 32 + lq * 8]);
                o[ni] = __builtin_amdgcn_mfma_f32_16x16x32_bf16(pf, vf, o[ni], 0, 0, 0);
            }
        }
        __syncthreads();
    }

    for (int ni = 0; ni < 4; ++ni)
        for (int j = 0; j < 4; ++j) {
            const int row = q0 + wave * 16 + lq * 4 + j;
            const int col = h * 64 + ni * 16 + lr;
            O[(size_t)(b * SEQ + row) * DIN + col] = (bf16)(o[ni][j] / lrow[j]);
        }
}

// ---------------------------------------------------------------------------
// Fused residual add + LayerNorm over D=512. X fp32, Y bf16.
// Writes bf16 (if Ob) and fp32 (if Of). One wave per row.
// ---------------------------------------------------------------------------
__global__ __launch_bounds__(256) void add_ln(const float* __restrict__ X,
                                              const bf16* __restrict__ Y,
                                              bf16* __restrict__ Ob,
                                              float* __restrict__ Of)
{
    const int row  = blockIdx.x * 4 + (threadIdx.x >> 6);
    const int lane = threadIdx.x & 63;
    const size_t base = (size_t)row * DIN + lane * 8;
    const float4 x0 = *reinterpret_cast<const float4*>(X + base);
    const float4 x1 = *reinterpret_cast<const float4*>(X + base + 4);
    const bf16x8 yv = *reinterpret_cast<const bf16x8*>(Y + base);
    float v[8] = {x0.x, x0.y, x0.z, x0.w, x1.x, x1.y, x1.z, x1.w};
    float s = 0.f;
    for (int i = 0; i < 8; ++i) { v[i] += (float)yv[i]; s += v[i]; }
    for (int off = 1; off < 64; off <<= 1) s += __shfl_xor(s, off);
    const float mu = s * (1.f / DIN);
    float var = 0.f;
    for (int i = 0; i < 8; ++i) { const float d = v[i] - mu; var += d * d; }
    for (int off = 1; off < 64; off <<= 1) var += __shfl_xor(var, off);
    const float rstd = rsqrtf(var * (1.f / DIN) + 1e-5f);
    float r[8];
    for (int i = 0; i < 8; ++i) r[i] = (v[i] - mu) * rstd;
    if (Ob) {
        bf16x8 ov;
        for (int i = 0; i < 8; ++i) ov[i] = (bf16)r[i];
        *reinterpret_cast<bf16x8*>(Ob + base) = ov;
    }
    if (Of) {
        *reinterpret_cast<float4*>(Of + base)     = make_float4(r[0], r[1], r[2], r[3]);
        *reinterpret_cast<float4*>(Of + base + 4) = make_float4(r[4], r[5], r[6], r[7]);
    }
}

// ---------------------------------------------------------------------------
extern "C" void kernel_launch(void* const* d_in, const int* in_sizes, int n_in,
                              void* d_out, int out_size, void* d_ws, size_t ws_size,
                              hipStream_t stream)
{
    const float* query = (const float*)d_in[0];
    const float* key   = (const float*)d_in[1];
    const float* value = (const float*)d_in[2];
    const float* mask  = (const float*)d_in[3];
    const float* WQ    = (const float*)d_in[4];
    const float* WK    = (const float*)d_in[5];
    const float* WV    = (const float*)d_in[6];
    const float* WO    = (const float*)d_in[7];
    const float* W1    = (const float*)d_in[8];
    const float* W2    = (const float*)d_in[9];

    char* w = (char*)d_ws;
    size_t off = 0;
    auto carve2 = [&](size_t elems) { bf16* p = (bf16*)(w + off); off += elems * 2; return p; };
    auto carve4 = [&](size_t elems) { float* p = (float*)(w + off); off += elems * 4; return p; };

    bf16* qc    = carve2((size_t)MROWS * DIN);
    bf16* kc    = carve2((size_t)MROWS * DIN);
    bf16* vc    = carve2((size_t)MROWS * DIN);
    bf16* Qb    = carve2((size_t)MROWS * DIN);
    bf16* Kb    = carve2((size_t)MROWS * DIN);
    bf16* Vb    = carve2((size_t)MROWS * DIN);
    bf16* Vt    = carve2((size_t)MROWS * DIN);
    bf16* Mid   = carve2((size_t)MROWS * DMID);
    float* Ln1f = carve4((size_t)MROWS * DIN);
    bf16* WQt   = carve2((size_t)DIN * DIN);
    bf16* WKt   = carve2((size_t)DIN * DIN);
    bf16* WVt   = carve2((size_t)DIN * DIN);
    bf16* WOt   = carve2((size_t)DIN * DIN);
    bf16* W1t   = carve2((size_t)DIN * DMID);
    bf16* W2t   = carve2((size_t)DMID * DIN);
    if (off > ws_size) return;

    // aliases of dead buffers
    bf16* Ob   = qc;   // attention output (qc dead after Q projection)
    bf16* Two  = kc;   // WO-proj output  (kc dead after K projection)
    bf16* Ln1b = vc;   // LN1 bf16        (vc dead after V projection)
    bf16* F2   = Vb;   // FFN output      (Vb dead after V transpose)

    const dim3 blk(256);
    const int nqkv = MROWS * DIN;

    // input casts -> bf16
    cast_f2b<<<dim3(nqkv / 1024), blk, 0, stream>>>(query, qc, nqkv);
    cast_f2b<<<dim3(nqkv / 1024), blk, 0, stream>>>(key,   kc, nqkv);
    cast_f2b<<<dim3(nqkv / 1024), blk, 0, stream>>>(value, vc, nqkv);

    // weight cast+transpose to [n][k]
    transpose_f2b<<<dim3(DIN / 32, DIN / 32), blk, 0, stream>>>(WQ, WQt, DIN, DIN);
    transpose_f2b<<<dim3(DIN / 32, DIN / 32), blk, 0, stream>>>(WK, WKt, DIN, DIN);
    transpose_f2b<<<dim3(DIN / 32, DIN / 32), blk, 0, stream>>>(WV, WVt, DIN, DIN);
    transpose_f2b<<<dim3(DIN / 32, DIN / 32), blk, 0, stream>>>(WO, WOt, DIN, DIN);
    transpose_f2b<<<dim3(DMID / 32, DIN / 32), blk, 0, stream>>>(W1, W1t, DMID, DIN);
    transpose_f2b<<<dim3(DIN / 32, DMID / 32), blk, 0, stream>>>(W2, W2t, DIN, DMID);

    // projections (N=512 -> 64x64 tiles, 1024 blocks)
    gemm64<0><<<dim3(DIN / 64, MROWS / 64), blk, 0, stream>>>(qc, WQt, Qb, MROWS, DIN, DIN);
    gemm64<0><<<dim3(DIN / 64, MROWS / 64), blk, 0, stream>>>(kc, WKt, Kb, MROWS, DIN, DIN);
    gemm64<0><<<dim3(DIN / 64, MROWS / 64), blk, 0, stream>>>(vc, WVt, Vb, MROWS, DIN, DIN);

    // V -> Vt[h*64+d][b*L+l]
    transpose_b2b<<<dim3(DIN / 32, MROWS / 32), blk, 0, stream>>>(Vb, Vt, DIN, MROWS);

    // attention
    attn_kernel<<<dim3(SEQ / 64, NHEAD, BATCH), blk, 0, stream>>>(Qb, Kb, Vt, mask, Ob);

    // output projection + residual + LN (keep fp32 copy for residual 2)
    gemm64<0><<<dim3(DIN / 64, MROWS / 64), blk, 0, stream>>>(Ob, WOt, Two, MROWS, DIN, DIN);
    add_ln<<<dim3(MROWS / 4), blk, 0, stream>>>(query, Two, Ln1b, Ln1f);

    // FFN
    gemm_bt<1><<<dim3(DMID / 128, MROWS / 128), blk, 0, stream>>>(Ln1b, W1t, Mid, MROWS, DMID, DIN);
    gemm64<0><<<dim3(DIN / 64, MROWS / 64), blk, 0, stream>>>(Mid, W2t, F2, MROWS, DIN, DMID);

    // final residual + LN -> fp32 output
    add_ln<<<dim3(MROWS / 4), blk, 0, stream>>>(Ln1f, F2, (bf16*)nullptr, (float*)d_out);
}